// Round 8
// baseline (79.678 us; speedup 1.0000x reference)
//
#include <hip/hip_runtime.h>
#include <math.h>

// KAN layer via bf16 MFMA GEMM, full-K per block (no split-K, no reduce):
//   out[b,o] = sum_k Feat[b,k]*W[k,o], K=1536
//   W[i*12+g][o] = sf[i,o]*cp[i,o,g] (g<11);  W[i*12+11][o] = sf[i,o]
//   Feat[b,i*12+g] = uniform cubic B-spline closed form; Feat[..11]=silu.
// 2 dispatches: prep (W -> bf16, B-fragment-swizzled in d_ws), gemm
// (16-row x 128-col block, K=1536: features->LDS A-tile -> 96 MFMA -> OUT).
// Fit from R1..R7: harness floor ~60 us (256MiB ws poison-fill = 40 us) +
// ~3 us/dispatch; the lever is dispatch count + eliminating partial traffic.
// MFMA layouts (HW-verified, learn_hip m89/m91/m120):
//   A[m=lane&15][k=(lane>>4)*8+j], B[k=(lane>>4)*8+j][n=lane&15],
//   D[row=(lane>>4)*4+q][col=lane&15].

#define IN_DIM   128
#define OUT_DIM  128
#define NCP      11
#define FS       12
#define KTOT     (IN_DIM * FS)      // 1536
#define MT       16                 // rows per gemm block
#define NSTEP    (KTOT / 32)        // 48 k-steps
#define ASTR     1544               // A-tile row stride (ushorts): 1536+8,
                                    // 16B-aligned rows, bank-balanced b128

typedef __attribute__((ext_vector_type(8))) short short8;
typedef __attribute__((ext_vector_type(4))) float f32x4;

static __device__ __forceinline__ unsigned short f2bf(float f) {
    unsigned int x = __float_as_uint(f);
    unsigned int r = (x + 0x7fffu + ((x >> 16) & 1u)) >> 16;   // RNE
    return (unsigned short)r;
}

// ---------- prep: Wz in B-fragment order, bf16 ----------
// Wz[((s*8 + t)*64 + lane)*8 + j]  for k = 32*s + 8*(lane>>4) + j, n = 16*t + (lane&15)
__global__ __launch_bounds__(256)
void kan_prep(const float* __restrict__ CP, const float* __restrict__ SF,
              unsigned short* __restrict__ Wz)
{
    const int idx  = blockIdx.x * 256 + threadIdx.x;  // 24576
    const int s    = idx >> 9;
    const int rem  = idx & 511;
    const int t    = rem >> 6;
    const int lane = rem & 63;
    const int o     = 16 * t + (lane & 15);
    const int kbase = 32 * s + 8 * (lane >> 4);

    unsigned int q[4];
    #pragma unroll
    for (int jj = 0; jj < 4; ++jj) {
        unsigned short lo = 0, hi = 0;
        #pragma unroll
        for (int half = 0; half < 2; ++half) {
            const int k = kbase + 2 * jj + half;
            const int i = k / 12;
            const int g = k - 12 * i;
            const float sf = SF[i * OUT_DIM + o];
            const float v  = (g == NCP) ? sf : sf * CP[(i * OUT_DIM + o) * NCP + g];
            if (half == 0) lo = f2bf(v); else hi = f2bf(v);
        }
        q[jj] = (unsigned int)lo | ((unsigned int)hi << 16);
    }
    *(uint4*)&Wz[idx * 8] = make_uint4(q[0], q[1], q[2], q[3]);
}

// ---------- gemm: full-K, writes OUT directly ----------
__global__ __launch_bounds__(256)
void kan_gemm(const float* __restrict__ X, const float* __restrict__ GR,
              const unsigned short* __restrict__ Wz, float* __restrict__ OUT)
{
    __shared__ __align__(16) unsigned short A[MT * ASTR];   // 48.25 KB

    const int tid = threadIdx.x;
    const int m0  = blockIdx.x * MT;

    const float t0   = GR[0];
    const float invh = 1.0f / (GR[1] - t0);

    // ---- Phase 1: features for 16 rows x 128 i's -> LDS A-tile ----
    #pragma unroll
    for (int kq = 0; kq < (MT * IN_DIM) / 256; ++kq) {     // 8 iters
        const int p_ = tid + kq * 256;        // (r,i)
        const int r  = p_ >> 7;
        const int i  = p_ & (IN_DIM - 1);

        const float x  = X[(m0 + r) * IN_DIM + i];
        const float xr = (x - t0) * invh;
        const float pf = floorf(xr);
        const int   p  = (int)pf;
        const float u  = xr - pf;
        const float um = 1.0f - u;
        const float u2 = u * u, u3 = u2 * u;
        const float c0 = um * um * um * (1.0f / 6.0f);
        const float c1 = (3.0f * u3 - 6.0f * u2 + 4.0f) * (1.0f / 6.0f);
        const float c2 = (-3.0f * u3 + 3.0f * u2 + 3.0f * u + 1.0f) * (1.0f / 6.0f);
        const float c3 = u3 * (1.0f / 6.0f);
        const float silu = x / (1.0f + __expf(-x));

        const bool ok = (p >= 0) && (p <= 13);
        const int  j0 = ok ? (p - 3) : -999;
        const int  pp = ok ? p : -999;

        unsigned short us[FS];
        #pragma unroll
        for (int g = 0; g < NCP; ++g) {
            float v = (g == j0)     ? c0
                    : (g == j0 + 1) ? c1
                    : (g == j0 + 2) ? c2
                    : (g == pp)     ? c3 : 0.0f;
            us[g] = f2bf(v);
        }
        us[NCP] = f2bf(silu);

        uint2* dst = (uint2*)&A[r * ASTR + i * FS];        // 8B-aligned
        dst[0] = make_uint2((unsigned)us[0] | ((unsigned)us[1] << 16),
                            (unsigned)us[2] | ((unsigned)us[3] << 16));
        dst[1] = make_uint2((unsigned)us[4] | ((unsigned)us[5] << 16),
                            (unsigned)us[6] | ((unsigned)us[7] << 16));
        dst[2] = make_uint2((unsigned)us[8] | ((unsigned)us[9] << 16),
                            (unsigned)us[10] | ((unsigned)us[11] << 16));
    }
    __syncthreads();

    // ---- Phase 2: wave w covers cols 32w..32w+31 (2 n-frags), all K ----
    const int lane = tid & 63;
    const int w    = tid >> 6;
    const int row  = lane & 15;
    const int quad = lane >> 4;

    f32x4 acc0 = (f32x4){0.f, 0.f, 0.f, 0.f};
    f32x4 acc1 = (f32x4){0.f, 0.f, 0.f, 0.f};

    const unsigned short* ab = &A[row * ASTR];
    #pragma unroll 8
    for (int s = 0; s < NSTEP; ++s) {
        const short8 a  = *(const short8*)(ab + s * 32 + 8 * quad);  // 16B-aligned
        const unsigned short* b = Wz + (size_t)((s * 8 + 2 * w) * 64 + lane) * 8;
        const short8 bA = *(const short8*)(b);
        const short8 bB = *(const short8*)(b + 64 * 8);
        acc0 = __builtin_amdgcn_mfma_f32_16x16x32_bf16(a, bA, acc0, 0, 0, 0);
        acc1 = __builtin_amdgcn_mfma_f32_16x16x32_bf16(a, bB, acc1, 0, 0, 0);
    }

    // ---- Epilogue: D[row=quad*4+q][col=lane&15] -> OUT ----
    #pragma unroll
    for (int q = 0; q < 4; ++q) {
        const int rr = m0 + 4 * quad + q;
        OUT[rr * OUT_DIM + 16 * (2 * w + 0) + row] = acc0[q];
        OUT[rr * OUT_DIM + 16 * (2 * w + 1) + row] = acc1[q];
    }
}

extern "C" void kernel_launch(void* const* d_in, const int* in_sizes, int n_in,
                              void* d_out, int out_size, void* d_ws, size_t ws_size,
                              hipStream_t stream) {
    const float* x  = (const float*)d_in[0];   // [B,128]
    const float* cp = (const float*)d_in[1];   // [128,128,11]
    const float* sf = (const float*)d_in[2];   // [128,128]
    const float* gr = (const float*)d_in[3];   // [128,128,15]
    float* out = (float*)d_out;

    const int batch = in_sizes[0] / IN_DIM;    // 1024

    unsigned short* Wz = (unsigned short*)d_ws;           // 384 KB

    kan_prep<<<(NSTEP * 8 * 64) / 256, 256, 0, stream>>>(cp, sf, Wz); // 96 blocks
    kan_gemm<<<batch / MT, 256, 0, stream>>>(x, gr, Wz, out);         // 64 blocks
}

// Round 9
// 69.328 us; speedup vs baseline: 1.1493x; 1.1493x over previous
//
#include <hip/hip_runtime.h>
#include <math.h>

// KAN layer via bf16 MFMA GEMM, full-K per block, N-split grid:
//   out[b,o] = sum_k Feat[b,k]*W[k,o], K=1536
//   W[i*12+g][o] = sf[i,o]*cp[i,o,g] (g<11);  W[i*12+11][o] = sf[i,o]
//   Feat[b,i*12+g] = uniform cubic B-spline closed form; Feat[..11]=silu.
// 2 dispatches: prep (W -> bf16 B-fragment order in d_ws), gemm.
// R9 vs R8: grid 64 -> 256 blocks (split N by 4: 16 rows x 32 cols, full K),
// waves split K 4-way + LDS reduce; all 24 B-frag loads issued BEFORE the
// feature phase so L2/L3 latency drains behind phase-1 VALU.
// MFMA layouts (HW-verified, learn_hip m89/m91/m120):
//   A[m=lane&15][k=(lane>>4)*8+j], B[k=(lane>>4)*8+j][n=lane&15],
//   D[row=(lane>>4)*4+q][col=lane&15].

#define IN_DIM   128
#define OUT_DIM  128
#define NCP      11
#define FS       12
#define KTOT     (IN_DIM * FS)      // 1536
#define MT       16                 // rows per block
#define NT       32                 // cols per block (2 n-frags)
#define NSTEP    (KTOT / 32)        // 48 k-steps total
#define WSTEP    (NSTEP / 4)        // 12 k-steps per wave
#define ASTR     1544               // A-tile row stride (ushorts), 16B-aligned

typedef __attribute__((ext_vector_type(8))) short short8;
typedef __attribute__((ext_vector_type(4))) float f32x4;

static __device__ __forceinline__ unsigned short f2bf(float f) {
    unsigned int x = __float_as_uint(f);
    unsigned int r = (x + 0x7fffu + ((x >> 16) & 1u)) >> 16;   // RNE
    return (unsigned short)r;
}

// ---------- prep: Wz in B-fragment order, bf16 (unchanged from R8) ----------
// Wz[((s*8 + t)*64 + lane)*8 + j]; k = 32*s + 8*(lane>>4) + j, n = 16*t + (lane&15)
__global__ __launch_bounds__(256)
void kan_prep(const float* __restrict__ CP, const float* __restrict__ SF,
              unsigned short* __restrict__ Wz)
{
    const int idx  = blockIdx.x * 256 + threadIdx.x;  // 24576
    const int s    = idx >> 9;
    const int rem  = idx & 511;
    const int t    = rem >> 6;
    const int lane = rem & 63;
    const int o     = 16 * t + (lane & 15);
    const int kbase = 32 * s + 8 * (lane >> 4);

    unsigned int q[4];
    #pragma unroll
    for (int jj = 0; jj < 4; ++jj) {
        unsigned short lo = 0, hi = 0;
        #pragma unroll
        for (int half = 0; half < 2; ++half) {
            const int k = kbase + 2 * jj + half;
            const int i = k / 12;
            const int g = k - 12 * i;
            const float sf = SF[i * OUT_DIM + o];
            const float v  = (g == NCP) ? sf : sf * CP[(i * OUT_DIM + o) * NCP + g];
            if (half == 0) lo = f2bf(v); else hi = f2bf(v);
        }
        q[jj] = (unsigned int)lo | ((unsigned int)hi << 16);
    }
    *(uint4*)&Wz[idx * 8] = make_uint4(q[0], q[1], q[2], q[3]);
}

// ---------- gemm: 16 rows x 32 cols per block, full K, K split across waves --
__global__ __launch_bounds__(256)
void kan_gemm(const float* __restrict__ X, const float* __restrict__ GR,
              const unsigned short* __restrict__ Wz, float* __restrict__ OUT)
{
    __shared__ __align__(16) unsigned short A[MT * ASTR];   // 48.25 KB

    const int tid = threadIdx.x;
    const int m0  = blockIdx.x * MT;
    const int nb  = blockIdx.y;           // n-block: cols 32*nb..32*nb+31
    const int n0  = NT * nb;

    const int lane = tid & 63;
    const int w    = tid >> 6;            // wave -> k-range 12*w..12*w+11
    const int r15  = lane & 15;
    const int quad = lane >> 4;

    // ---- B prefetch: all 24 fragment loads issued BEFORE phase 1 ----
    short8 breg0[WSTEP], breg1[WSTEP];
    #pragma unroll
    for (int sl = 0; sl < WSTEP; ++sl) {
        const int s = WSTEP * w + sl;
        const unsigned short* b =
            Wz + (size_t)(((s * 8) + 2 * nb) * 64 + lane) * 8;
        breg0[sl] = *(const short8*)(b);
        breg1[sl] = *(const short8*)(b + 64 * 8);
    }

    // ---- Phase 1: features for 16 rows x 128 i -> LDS A-tile ----
    const float t0   = GR[0];
    const float invh = 1.0f / (GR[1] - t0);

    #pragma unroll
    for (int kq = 0; kq < (MT * IN_DIM) / 256; ++kq) {     // 8 iters
        const int p_ = tid + kq * 256;
        const int r  = p_ >> 7;
        const int i  = p_ & (IN_DIM - 1);

        const float x  = X[(m0 + r) * IN_DIM + i];
        const float xr = (x - t0) * invh;
        const float pf = floorf(xr);
        const int   p  = (int)pf;
        const float u  = xr - pf;
        const float um = 1.0f - u;
        const float u2 = u * u, u3 = u2 * u;
        const float c0 = um * um * um * (1.0f / 6.0f);
        const float c1 = (3.0f * u3 - 6.0f * u2 + 4.0f) * (1.0f / 6.0f);
        const float c2 = (-3.0f * u3 + 3.0f * u2 + 3.0f * u + 1.0f) * (1.0f / 6.0f);
        const float c3 = u3 * (1.0f / 6.0f);
        const float silu = x / (1.0f + __expf(-x));

        const bool ok = (p >= 0) && (p <= 13);
        const int  j0 = ok ? (p - 3) : -999;
        const int  pp = ok ? p : -999;

        unsigned short us[FS];
        #pragma unroll
        for (int g = 0; g < NCP; ++g) {
            float v = (g == j0)     ? c0
                    : (g == j0 + 1) ? c1
                    : (g == j0 + 2) ? c2
                    : (g == pp)     ? c3 : 0.0f;
            us[g] = f2bf(v);
        }
        us[NCP] = f2bf(silu);

        uint2* dst = (uint2*)&A[r * ASTR + i * FS];        // 8B-aligned
        dst[0] = make_uint2((unsigned)us[0] | ((unsigned)us[1] << 16),
                            (unsigned)us[2] | ((unsigned)us[3] << 16));
        dst[1] = make_uint2((unsigned)us[4] | ((unsigned)us[5] << 16),
                            (unsigned)us[6] | ((unsigned)us[7] << 16));
        dst[2] = make_uint2((unsigned)us[8] | ((unsigned)us[9] << 16),
                            (unsigned)us[10] | ((unsigned)us[11] << 16));
    }
    __syncthreads();

    // ---- Phase 2: 12 MFMA steps per wave over its K range ----
    f32x4 acc0 = (f32x4){0.f, 0.f, 0.f, 0.f};
    f32x4 acc1 = (f32x4){0.f, 0.f, 0.f, 0.f};

    const unsigned short* ab = &A[r15 * ASTR];
    #pragma unroll
    for (int sl = 0; sl < WSTEP; ++sl) {
        const int s = WSTEP * w + sl;
        const short8 a = *(const short8*)(ab + s * 32 + 8 * quad);  // 16B-aligned
        acc0 = __builtin_amdgcn_mfma_f32_16x16x32_bf16(a, breg0[sl], acc0, 0, 0, 0);
        acc1 = __builtin_amdgcn_mfma_f32_16x16x32_bf16(a, breg1[sl], acc1, 0, 0, 0);
    }

    // ---- cross-wave K reduction in LDS (reuse A region) ----
    __syncthreads();                       // all A reads done
    float* red = (float*)A;                // red[w*528 + m*33 + n], 8448 B
    #pragma unroll
    for (int q = 0; q < 4; ++q) {
        const int m = quad * 4 + q;
        red[w * 528 + m * 33 + r15]      = acc0[q];
        red[w * 528 + m * 33 + 16 + r15] = acc1[q];
    }
    __syncthreads();

    // ---- final sum + store: 512 outputs over 256 threads ----
    #pragma unroll
    for (int e = tid; e < MT * NT; e += 256) {
        const int m = e >> 5;
        const int n = e & 31;
        float v = 0.0f;
        #pragma unroll
        for (int ww = 0; ww < 4; ++ww)
            v += red[ww * 528 + m * 33 + n];
        OUT[(m0 + m) * OUT_DIM + n0 + n] = v;
    }
}

extern "C" void kernel_launch(void* const* d_in, const int* in_sizes, int n_in,
                              void* d_out, int out_size, void* d_ws, size_t ws_size,
                              hipStream_t stream) {
    const float* x  = (const float*)d_in[0];   // [B,128]
    const float* cp = (const float*)d_in[1];   // [128,128,11]
    const float* sf = (const float*)d_in[2];   // [128,128]
    const float* gr = (const float*)d_in[3];   // [128,128,15]
    float* out = (float*)d_out;

    const int batch = in_sizes[0] / IN_DIM;    // 1024

    unsigned short* Wz = (unsigned short*)d_ws;           // 384 KB

    kan_prep<<<(NSTEP * 8 * 64) / 256, 256, 0, stream>>>(cp, sf, Wz); // 96 blocks
    dim3 grid(batch / MT, OUT_DIM / NT);                  // (64,4) = 256 blocks
    kan_gemm<<<grid, 256, 0, stream>>>(x, gr, Wz, out);
}